// Round 6
// baseline (625.615 us; speedup 1.0000x reference)
//
#include <hip/hip_runtime.h>
#include <stdint.h>

// ---------------------------------------------------------------------------
// R6: wave-autonomous pipeline — ZERO __syncthreads in the hot kernels.
//  chunk = 16 pixels = one wave's MFMA m-tile. Each wave, independently:
//   prologue: carry prefix from prev dispatch (<=63 GT rows + <=63 A64 rows)
//   basefold: base = bias + INVN * (W^T . carry)   (Wr native [d][f] layout)
//   MFMA dense (f16, fp32 acc) -> relu -> in-lane + shuffle scan (16 px)
//   publish chunk aggregate: A64[chunk] store + atomicAdd GT[group]
//   in-pixel channel combine -> wave-private LDS transpose -> coalesced store
//  Cross-wave sync: NONE (intra-wave DS ops are in-order; defensive
//  s_waitcnt lgkmcnt(0) fences). Cross-dispatch carries only.
//  Dispatches: memset(GT) -> prep -> midA(L0 LUT+dense1) -> midB(dense2)
//              -> midC(dense3 + final MFMA -> out) -> fixk(out += Wf.carry3)
// ---------------------------------------------------------------------------

#define BB 4
#define SP 65536
#define SS 196608
#define INVN (1.0f / 196608.0f)

typedef __attribute__((ext_vector_type(8))) _Float16 half8;
typedef __attribute__((ext_vector_type(4))) float    f32x4;

__device__ __forceinline__ void wavefence() {
    __builtin_amdgcn_wave_barrier();
    __builtin_amdgcn_s_waitcnt(0xC07F);   // lgkmcnt(0), vmcnt/expcnt untouched
    __builtin_amdgcn_wave_barrier();
}

// ---------------- prep: histograms + weight transposes ----------------------
__global__ __launch_bounds__(256)
void prep(const int* __restrict__ ex, const float* __restrict__ W0,
          const float* __restrict__ b0, const float* __restrict__ Wr,
          const float* __restrict__ Wfin,
          _Float16* __restrict__ Wt16, _Float16* __restrict__ Wf16p,
          float* __restrict__ Wf32, float* __restrict__ tab32,
          int* __restrict__ Hsub, int* __restrict__ HG)
{
    __shared__ int hist[64][24];
    int tid = threadIdx.x, bi = blockIdx.x;
    int b = bi >> 6, g = bi & 63;              // group = 1024 px
    for (int i = tid; i < 1536; i += 256) hist[i / 24][i % 24] = 0;
    __syncthreads();
    for (int q = 0; q < 4; ++q) {
        int p = g * 1024 + q * 256 + tid;      // pixel within batch
        const int* ep = ex + ((size_t)b * SP + p) * 3;
        int j = (p >> 4) & 63;                 // 16-px chunk within group
        atomicAdd(&hist[j][ep[0]], 1);
        atomicAdd(&hist[j][8 + ep[1]], 1);
        atomicAdd(&hist[j][16 + ep[2]], 1);
    }
    __syncthreads();
    for (int i = tid; i < 1536; i += 256) {
        int j = i / 24, cv = i % 24;
        Hsub[(size_t)((b << 12) | (g << 6) | j) * 24 + cv] = hist[j][cv];
    }
    if (tid < 24) {
        int s = 0;
        for (int j = 0; j < 64; ++j) s += hist[j][tid];
        HG[(size_t)((b << 6) | g) * 24 + tid] = s;
    }
    if (bi < 64) {
        int i0 = bi * 256 + tid, nth = 64 * 256;
        for (int idx = i0; idx < 36864; idx += nth) {   // Wt16[l][c][f][d]
            int d = idx & 63, f = (idx >> 6) & 63, lc = idx >> 12;
            Wt16[idx] = (_Float16)Wr[(size_t)(lc * 64 + d) * 64 + f];
        }
        for (int idx = i0; idx < 3072; idx += nth) {    // Wf16p[c][n16][d]
            int d = idx & 63, n = (idx >> 6) & 15, c = idx >> 10;
            Wf16p[idx] = (n < 8) ? (_Float16)Wfin[(size_t)(c * 64 + d) * 8 + n]
                                 : (_Float16)0.f;
        }
        for (int idx = i0; idx < 1536; idx += nth) {    // Wf32[ck][d]
            int d = idx & 63, ck = idx >> 6;
            Wf32[idx] = Wfin[(size_t)((ck >> 3) * 64 + d) * 8 + (ck & 7)];
        }
        for (int idx = i0; idx < 1536; idx += nth) {    // tab32[cv][f]
            int f = idx & 63, v = (idx >> 6) & 7, c = idx >> 9;
            float xv = v * 0.25f - 1.0f;
            tab32[idx] = fmaxf(W0[c * 64 + f] * xv + b0[c * 64 + f], 0.f);
        }
    }
}

// ---------------- midA: layer0 LUT + dense1 -> Y1 ---------------------------
__global__ __launch_bounds__(256, 3)
void midA(const int* __restrict__ ex,
          const int* __restrict__ Hsub, const int* __restrict__ HG,
          const float* __restrict__ tab32,
          const _Float16* __restrict__ W16, const float* __restrict__ Wd32,
          const float* __restrict__ bias, _Float16* __restrict__ Y,
          float* __restrict__ A64, float* __restrict__ GT)
{
    __shared__ float carry[4][64];
    __shared__ float fcnt[4][24];
    __shared__ float basearr[4][192];
    __shared__ __align__(16) _Float16 bounce[4][16 * 72];

    int tid = threadIdx.x, w = tid >> 6, ln = tid & 63, lm = ln & 15, lq = ln >> 4;
    int tk = blockIdx.x * 4 + w;
    int b = tk >> 12, ci = tk & 4095;
    int g = ci >> 6, cr = ci & 63;
    int P0 = ci * 16;

    // hist prefix (lanes < 24)
    if (ln < 24) {
        int ic = 0;
        for (int j = 0; j < g; ++j) ic += HG[(size_t)((b << 6) | j) * 24 + ln];
        const int* hp = Hsub + (size_t)((b << 12) | (g << 6)) * 24 + ln;
        for (int j = 0; j < cr; ++j) ic += hp[j * 24];
        fcnt[w][ln] = (float)ic;
    }
    wavefence();
    {   // layer-0 carry[f] from histogram counts
        float c0 = 0.f;
#pragma unroll
        for (int cv = 0; cv < 24; ++cv)
            c0 += fcnt[w][cv] * tab32[cv * 64 + ln];
        carry[w][ln] = c0;
    }
    wavefence();
    {   // basefold for dense1
        float a0 = 0.f, a1 = 0.f, a2 = 0.f;
        for (int d = 0; d < 64; ++d) {
            float cd = carry[w][d];
            a0 += cd * Wd32[(size_t)(0 * 64 + d) * 64 + ln];
            a1 += cd * Wd32[(size_t)(1 * 64 + d) * 64 + ln];
            a2 += cd * Wd32[(size_t)(2 * 64 + d) * 64 + ln];
        }
        basearr[w][ln]       = bias[ln]       + INVN * a0;
        basearr[w][64 + ln]  = bias[64 + ln]  + INVN * a1;
        basearr[w][128 + ln] = bias[128 + ln] + INVN * a2;
    }
    wavefence();

    // layer-0: LUT values + local scan (chunk = this wave's 16 px)
    float s[3][4][4], off[3][4];
    {
        float run[3][4];
#pragma unroll
        for (int c = 0; c < 3; ++c)
#pragma unroll
            for (int nt = 0; nt < 4; ++nt) run[c][nt] = 0.f;
#pragma unroll
        for (int r = 0; r < 4; ++r) {
            const int* ep = ex + ((size_t)b * SP + P0 + lq * 4 + r) * 3;
            int v0 = ep[0], v1 = ep[1], v2 = ep[2];
#pragma unroll
            for (int nt = 0; nt < 4; ++nt) {
                run[0][nt] += tab32[(v0) * 64 + nt * 16 + lm];       s[0][nt][r] = run[0][nt];
                run[1][nt] += tab32[(8 + v1) * 64 + nt * 16 + lm];   s[1][nt][r] = run[1][nt];
                run[2][nt] += tab32[(16 + v2) * 64 + nt * 16 + lm];  s[2][nt][r] = run[2][nt];
            }
        }
#pragma unroll
        for (int c = 0; c < 3; ++c)
#pragma unroll
            for (int nt = 0; nt < 4; ++nt) {
                float v = s[c][nt][3];
                float t1 = __shfl_up(v, 16); if (lq >= 1) v += t1;
                float t2 = __shfl_up(v, 32); if (lq >= 2) v += t2;
                off[c][nt] = v - s[c][nt][3];
            }
    }

    // combine -> bounce -> A-frags (wave-private, per channel)
    half8 a0f[3], a1f[3];
#pragma unroll
    for (int c = 0; c < 3; ++c) {
#pragma unroll
        for (int nt = 0; nt < 4; ++nt)
#pragma unroll
            for (int r = 0; r < 4; ++r) {
                float S0 = off[0][nt] + s[0][nt][r];
                float S1 = off[1][nt] + s[1][nt][r];
                float S2 = off[2][nt] + s[2][nt][r];
                float P1 = off[1][nt] + (r ? s[1][nt][r - 1] : 0.f);
                float P2 = off[2][nt] + (r ? s[2][nt][r - 1] : 0.f);
                float val = (c == 0) ? S0 + P1 + P2
                          : (c == 1) ? S0 + S1 + P2
                                     : S0 + S1 + S2;
                bounce[w][(lq * 4 + r) * 72 + nt * 16 + lm] = (_Float16)val;
            }
        wavefence();
        const half8* bb = (const half8*)&bounce[w][0];
        a0f[c] = bb[lm * 9 + lq];
        a1f[c] = bb[lm * 9 + 4 + lq];
        wavefence();
    }

    // dense1 MFMA
    f32x4 acc[3][4];
#pragma unroll
    for (int c = 0; c < 3; ++c)
#pragma unroll
        for (int nt = 0; nt < 4; ++nt) {
            const half8* bp = (const half8*)(W16 + (size_t)(c * 64 + nt * 16 + lm) * 64);
            f32x4 t = {0.f, 0.f, 0.f, 0.f};
            t = __builtin_amdgcn_mfma_f32_16x16x32_f16(a0f[c], bp[lq],     t, 0, 0, 0);
            t = __builtin_amdgcn_mfma_f32_16x16x32_f16(a1f[c], bp[4 + lq], t, 0, 0, 0);
            acc[c][nt] = t;
        }

    // relu + scan (layer-1)
    float vin[3][4];
#pragma unroll
    for (int c = 0; c < 3; ++c)
#pragma unroll
        for (int nt = 0; nt < 4; ++nt) {
            float base = basearr[w][c * 64 + nt * 16 + lm];
            float run = 0.f;
#pragma unroll
            for (int r = 0; r < 4; ++r) {
                float yv = fmaxf(base + INVN * acc[c][nt][r], 0.f);
                run += yv; s[c][nt][r] = run;
            }
            float v = run;
            float t1 = __shfl_up(v, 16); if (lq >= 1) v += t1;
            float t2 = __shfl_up(v, 32); if (lq >= 2) v += t2;
            off[c][nt] = v - run;
            vin[c][nt] = v;
        }
    if (lq == 3)
#pragma unroll
        for (int nt = 0; nt < 4; ++nt) {
            float t3 = vin[0][nt] + vin[1][nt] + vin[2][nt];
            A64[(size_t)tk * 64 + nt * 16 + lm] = t3;
            atomicAdd(&GT[(size_t)((b << 6) | g) * 64 + nt * 16 + lm], t3);
        }

    // combine -> bounce -> coalesced Y store
#pragma unroll
    for (int c = 0; c < 3; ++c) {
#pragma unroll
        for (int nt = 0; nt < 4; ++nt)
#pragma unroll
            for (int r = 0; r < 4; ++r) {
                float S0 = off[0][nt] + s[0][nt][r];
                float S1 = off[1][nt] + s[1][nt][r];
                float S2 = off[2][nt] + s[2][nt][r];
                float P1 = off[1][nt] + (r ? s[1][nt][r - 1] : 0.f);
                float P2 = off[2][nt] + (r ? s[2][nt][r - 1] : 0.f);
                float val = (c == 0) ? S0 + P1 + P2
                          : (c == 1) ? S0 + S1 + P2
                                     : S0 + S1 + S2;
                bounce[w][(lq * 4 + r) * 72 + nt * 16 + lm] = (_Float16)val;
            }
        wavefence();
        const half8* bb = (const half8*)&bounce[w][0];
        half8 v0 = bb[lm * 9 + lq], v1 = bb[lm * 9 + 4 + lq];
        half8* Yo = (half8*)(Y + ((size_t)(b * 3 + c) * SP + P0 + lm) * 64);
        Yo[lq] = v0; Yo[4 + lq] = v1;
        wavefence();
    }
}

// ---------------- midB: dense2, Y in-place ----------------------------------
__global__ __launch_bounds__(256, 4)
void midB(const _Float16* Yin, _Float16* Yout,
          const float* __restrict__ A64p, const float* __restrict__ GTp,
          const _Float16* __restrict__ W16, const float* __restrict__ Wd32,
          const float* __restrict__ bias,
          float* __restrict__ A64, float* __restrict__ GT)
{
    __shared__ float carry[4][64];
    __shared__ float basearr[4][192];
    __shared__ __align__(16) _Float16 bounce[4][16 * 72];

    int tid = threadIdx.x, w = tid >> 6, ln = tid & 63, lm = ln & 15, lq = ln >> 4;
    int tk = blockIdx.x * 4 + w;
    int b = tk >> 12, ci = tk & 4095;
    int g = ci >> 6, cr = ci & 63;
    int P0 = ci * 16;

    // A-frags early (hide latency behind prologue)
    half8 a0f[3], a1f[3];
#pragma unroll
    for (int c = 0; c < 3; ++c) {
        const half8* ap = (const half8*)(Yin + ((size_t)(b * 3 + c) * SP + P0 + lm) * 64);
        a0f[c] = ap[lq]; a1f[c] = ap[4 + lq];
    }

    // carry prefix
    {
        float cs = 0.f;
        for (int j = 0; j < g; ++j) cs += GTp[(size_t)((b << 6) | j) * 64 + ln];
        const float* ap = A64p + (size_t)((b << 12) | (g << 6)) * 64 + ln;
        for (int j = 0; j < cr; ++j) cs += ap[j * 64];
        carry[w][ln] = cs;
    }
    wavefence();
    {   // basefold
        float a0 = 0.f, a1 = 0.f, a2 = 0.f;
        for (int d = 0; d < 64; ++d) {
            float cd = carry[w][d];
            a0 += cd * Wd32[(size_t)(0 * 64 + d) * 64 + ln];
            a1 += cd * Wd32[(size_t)(1 * 64 + d) * 64 + ln];
            a2 += cd * Wd32[(size_t)(2 * 64 + d) * 64 + ln];
        }
        basearr[w][ln]       = bias[ln]       + INVN * a0;
        basearr[w][64 + ln]  = bias[64 + ln]  + INVN * a1;
        basearr[w][128 + ln] = bias[128 + ln] + INVN * a2;
    }
    wavefence();

    f32x4 acc[3][4];
#pragma unroll
    for (int c = 0; c < 3; ++c)
#pragma unroll
        for (int nt = 0; nt < 4; ++nt) {
            const half8* bp = (const half8*)(W16 + (size_t)(c * 64 + nt * 16 + lm) * 64);
            f32x4 t = {0.f, 0.f, 0.f, 0.f};
            t = __builtin_amdgcn_mfma_f32_16x16x32_f16(a0f[c], bp[lq],     t, 0, 0, 0);
            t = __builtin_amdgcn_mfma_f32_16x16x32_f16(a1f[c], bp[4 + lq], t, 0, 0, 0);
            acc[c][nt] = t;
        }

    float s[3][4][4], off[3][4], vin[3][4];
#pragma unroll
    for (int c = 0; c < 3; ++c)
#pragma unroll
        for (int nt = 0; nt < 4; ++nt) {
            float base = basearr[w][c * 64 + nt * 16 + lm];
            float run = 0.f;
#pragma unroll
            for (int r = 0; r < 4; ++r) {
                float yv = fmaxf(base + INVN * acc[c][nt][r], 0.f);
                run += yv; s[c][nt][r] = run;
            }
            float v = run;
            float t1 = __shfl_up(v, 16); if (lq >= 1) v += t1;
            float t2 = __shfl_up(v, 32); if (lq >= 2) v += t2;
            off[c][nt] = v - run;
            vin[c][nt] = v;
        }
    if (lq == 3)
#pragma unroll
        for (int nt = 0; nt < 4; ++nt) {
            float t3 = vin[0][nt] + vin[1][nt] + vin[2][nt];
            A64[(size_t)tk * 64 + nt * 16 + lm] = t3;
            atomicAdd(&GT[(size_t)((b << 6) | g) * 64 + nt * 16 + lm], t3);
        }

#pragma unroll
    for (int c = 0; c < 3; ++c) {
#pragma unroll
        for (int nt = 0; nt < 4; ++nt)
#pragma unroll
            for (int r = 0; r < 4; ++r) {
                float S0 = off[0][nt] + s[0][nt][r];
                float S1 = off[1][nt] + s[1][nt][r];
                float S2 = off[2][nt] + s[2][nt][r];
                float P1 = off[1][nt] + (r ? s[1][nt][r - 1] : 0.f);
                float P2 = off[2][nt] + (r ? s[2][nt][r - 1] : 0.f);
                float val = (c == 0) ? S0 + P1 + P2
                          : (c == 1) ? S0 + S1 + P2
                                     : S0 + S1 + S2;
                bounce[w][(lq * 4 + r) * 72 + nt * 16 + lm] = (_Float16)val;
            }
        wavefence();
        const half8* bb = (const half8*)&bounce[w][0];
        half8 v0 = bb[lm * 9 + lq], v1 = bb[lm * 9 + 4 + lq];
        half8* Yo = (half8*)(Yout + ((size_t)(b * 3 + c) * SP + P0 + lm) * 64);
        Yo[lq] = v0; Yo[4 + lq] = v1;
        wavefence();
    }
}

// ---------------- midC: dense3 + final MFMA -> out --------------------------
__global__ __launch_bounds__(256, 3)
void midC(const _Float16* __restrict__ Yin,
          const float* __restrict__ A64p, const float* __restrict__ GTp,
          const _Float16* __restrict__ W16, const float* __restrict__ Wd32,
          const float* __restrict__ bias,
          const _Float16* __restrict__ Wf16p, const float* __restrict__ bfin,
          float* __restrict__ out, float* __restrict__ A64, float* __restrict__ GT)
{
    __shared__ float carry[4][64];
    __shared__ float basearr[4][192];
    __shared__ __align__(16) _Float16 bounce[4][16 * 72];
    __shared__ __align__(16) float outst[4][16 * 28];

    int tid = threadIdx.x, w = tid >> 6, ln = tid & 63, lm = ln & 15, lq = ln >> 4;
    int tk = blockIdx.x * 4 + w;
    int b = tk >> 12, ci = tk & 4095;
    int g = ci >> 6, cr = ci & 63;
    int P0 = ci * 16;

    half8 a0f[3], a1f[3];
#pragma unroll
    for (int c = 0; c < 3; ++c) {
        const half8* ap = (const half8*)(Yin + ((size_t)(b * 3 + c) * SP + P0 + lm) * 64);
        a0f[c] = ap[lq]; a1f[c] = ap[4 + lq];
    }
    {
        float cs = 0.f;
        for (int j = 0; j < g; ++j) cs += GTp[(size_t)((b << 6) | j) * 64 + ln];
        const float* ap = A64p + (size_t)((b << 12) | (g << 6)) * 64 + ln;
        for (int j = 0; j < cr; ++j) cs += ap[j * 64];
        carry[w][ln] = cs;
    }
    wavefence();
    {
        float a0 = 0.f, a1 = 0.f, a2 = 0.f;
        for (int d = 0; d < 64; ++d) {
            float cd = carry[w][d];
            a0 += cd * Wd32[(size_t)(0 * 64 + d) * 64 + ln];
            a1 += cd * Wd32[(size_t)(1 * 64 + d) * 64 + ln];
            a2 += cd * Wd32[(size_t)(2 * 64 + d) * 64 + ln];
        }
        basearr[w][ln]       = bias[ln]       + INVN * a0;
        basearr[w][64 + ln]  = bias[64 + ln]  + INVN * a1;
        basearr[w][128 + ln] = bias[128 + ln] + INVN * a2;
    }
    wavefence();

    f32x4 acc[3][4];
#pragma unroll
    for (int c = 0; c < 3; ++c)
#pragma unroll
        for (int nt = 0; nt < 4; ++nt) {
            const half8* bp = (const half8*)(W16 + (size_t)(c * 64 + nt * 16 + lm) * 64);
            f32x4 t = {0.f, 0.f, 0.f, 0.f};
            t = __builtin_amdgcn_mfma_f32_16x16x32_f16(a0f[c], bp[lq],     t, 0, 0, 0);
            t = __builtin_amdgcn_mfma_f32_16x16x32_f16(a1f[c], bp[4 + lq], t, 0, 0, 0);
            acc[c][nt] = t;
        }

    float s[3][4][4], off[3][4], vin[3][4];
#pragma unroll
    for (int c = 0; c < 3; ++c)
#pragma unroll
        for (int nt = 0; nt < 4; ++nt) {
            float base = basearr[w][c * 64 + nt * 16 + lm];
            float run = 0.f;
#pragma unroll
            for (int r = 0; r < 4; ++r) {
                float yv = fmaxf(base + INVN * acc[c][nt][r], 0.f);
                run += yv; s[c][nt][r] = run;
            }
            float v = run;
            float t1 = __shfl_up(v, 16); if (lq >= 1) v += t1;
            float t2 = __shfl_up(v, 32); if (lq >= 2) v += t2;
            off[c][nt] = v - run;
            vin[c][nt] = v;
        }
    if (lq == 3)
#pragma unroll
        for (int nt = 0; nt < 4; ++nt) {
            float t3 = vin[0][nt] + vin[1][nt] + vin[2][nt];
            A64[(size_t)tk * 64 + nt * 16 + lm] = t3;
            atomicAdd(&GT[(size_t)((b << 6) | g) * 64 + nt * 16 + lm], t3);
        }

    // combine -> bounce -> final MFMA (Wf padded to n=16) -> outst
#pragma unroll
    for (int c = 0; c < 3; ++c) {
#pragma unroll
        for (int nt = 0; nt < 4; ++nt)
#pragma unroll
            for (int r = 0; r < 4; ++r) {
                float S0 = off[0][nt] + s[0][nt][r];
                float S1 = off[1][nt] + s[1][nt][r];
                float S2 = off[2][nt] + s[2][nt][r];
                float P1 = off[1][nt] + (r ? s[1][nt][r - 1] : 0.f);
                float P2 = off[2][nt] + (r ? s[2][nt][r - 1] : 0.f);
                float val = (c == 0) ? S0 + P1 + P2
                          : (c == 1) ? S0 + S1 + P2
                                     : S0 + S1 + S2;
                bounce[w][(lq * 4 + r) * 72 + nt * 16 + lm] = (_Float16)val;
            }
        wavefence();
        const half8* bb = (const half8*)&bounce[w][0];
        half8 fa0 = bb[lm * 9 + lq], fa1 = bb[lm * 9 + 4 + lq];
        const half8* fb = (const half8*)(Wf16p + (size_t)(c * 16 + lm) * 64);
        f32x4 t = {0.f, 0.f, 0.f, 0.f};
        t = __builtin_amdgcn_mfma_f32_16x16x32_f16(fa0, fb[lq],     t, 0, 0, 0);
        t = __builtin_amdgcn_mfma_f32_16x16x32_f16(fa1, fb[4 + lq], t, 0, 0, 0);
        if (lm < 8) {
            float bz = bfin[c * 8 + lm];
#pragma unroll
            for (int r = 0; r < 4; ++r)
                outst[w][(lq * 4 + r) * 28 + c * 8 + lm] = bz + INVN * t[r];
        }
        wavefence();
    }

    // coalesced out store: 16 px x 24 floats = 96 float4
    float4* obase = (float4*)(out + ((size_t)b * SS + (size_t)P0 * 3) * 8);
#pragma unroll
    for (int k = 0; k < 2; ++k) {
        int fi = ln + 64 * k;
        if (fi < 96) {
            int flat = fi * 4, pix = flat / 24, sub = flat - pix * 24;
            obase[fi] = *(const float4*)&outst[w][pix * 28 + sub];
        }
    }
}

// ---------------- fixk: out += INVN * Wf . carry3 ---------------------------
__global__ __launch_bounds__(256, 4)
void fixk(const float* __restrict__ A64p, const float* __restrict__ GTp,
          const float* __restrict__ Wf32, float* __restrict__ out)
{
    __shared__ float carry[4][64];
    __shared__ float vfix[4][24];
    int tid = threadIdx.x, w = tid >> 6, ln = tid & 63;
    int tk = blockIdx.x * 4 + w;
    int b = tk >> 12, ci = tk & 4095;
    int g = ci >> 6, cr = ci & 63;
    int P0 = ci * 16;

    {
        float cs = 0.f;
        for (int j = 0; j < g; ++j) cs += GTp[(size_t)((b << 6) | j) * 64 + ln];
        const float* ap = A64p + (size_t)((b << 12) | (g << 6)) * 64 + ln;
        for (int j = 0; j < cr; ++j) cs += ap[j * 64];
        carry[w][ln] = cs;
    }
    wavefence();
    if (ln < 24) {
        float vf = 0.f;
        for (int d = 0; d < 64; ++d) vf += carry[w][d] * Wf32[ln * 64 + d];
        vfix[w][ln] = INVN * vf;
    }
    wavefence();
    float4* obase = (float4*)(out + ((size_t)b * SS + (size_t)P0 * 3) * 8);
#pragma unroll
    for (int k = 0; k < 2; ++k) {
        int fi = ln + 64 * k;
        if (fi < 96) {
            int flat = fi * 4, pix = flat / 24, sub = flat - pix * 24;
            float4 v = obase[fi];
            v.x += vfix[w][sub];
            v.y += vfix[w][sub + 1];
            v.z += vfix[w][sub + 2];
            v.w += vfix[w][sub + 3];
            obase[fi] = v;
        }
    }
}

// ---------------- host -------------------------------------------------------
extern "C" void kernel_launch(void* const* d_in, const int* in_sizes, int n_in,
                              void* d_out, int out_size, void* d_ws, size_t ws_size,
                              hipStream_t stream)
{
    const int*   ex   = (const int*)d_in[0];
    const float* W0   = (const float*)d_in[1];
    const float* b0   = (const float*)d_in[2];
    const float* Wr   = (const float*)d_in[3];
    const float* br   = (const float*)d_in[4];
    const float* Wfin = (const float*)d_in[5];
    const float* bfin = (const float*)d_in[6];
    float* out = (float*)d_out;

    char* ws = (char*)d_ws;
    size_t off = 0;
    _Float16* Y = (_Float16*)(ws + off); off += (size_t)BB * 3 * SP * 64 * 2;  // 100.7 MB
    float* GT1 = (float*)(ws + off); off += 65536;
    float* GT2 = (float*)(ws + off); off += 65536;
    float* GT3 = (float*)(ws + off); off += 65536;
    float* A64_1 = (float*)(ws + off); off += (size_t)16384 * 64 * 4;
    float* A64_2 = (float*)(ws + off); off += (size_t)16384 * 64 * 4;
    float* A64_3 = (float*)(ws + off); off += (size_t)16384 * 64 * 4;
    int* Hsub = (int*)(ws + off); off += (size_t)16384 * 24 * 4;
    int* HG   = (int*)(ws + off); off += 256 * 24 * 4;
    _Float16* Wt16  = (_Float16*)(ws + off); off += 36864 * 2;
    _Float16* Wf16p = (_Float16*)(ws + off); off += 3072 * 2;
    float* Wf32  = (float*)(ws + off); off += 1536 * 4;
    float* tab32 = (float*)(ws + off); off += 1536 * 4;

    hipMemsetAsync(GT1, 0, 3 * 65536, stream);
    prep<<<256, 256, 0, stream>>>(ex, W0, b0, Wr, Wfin,
                                  Wt16, Wf16p, Wf32, tab32, Hsub, HG);
    midA<<<4096, 256, 0, stream>>>(ex, Hsub, HG, tab32,
                                   Wt16, Wr, br, Y, A64_1, GT1);
    midB<<<4096, 256, 0, stream>>>(Y, Y, A64_1, GT1,
                                   Wt16 + 12288, Wr + 12288, br + 192,
                                   A64_2, GT2);
    midC<<<4096, 256, 0, stream>>>(Y, A64_2, GT2,
                                   Wt16 + 24576, Wr + 24576, br + 384,
                                   Wf16p, bfin, out, A64_3, GT3);
    fixk<<<4096, 256, 0, stream>>>(A64_3, GT3, Wf32, out);
}

// Round 7
// 364.528 us; speedup vs baseline: 1.7162x; 1.7162x over previous
//
#include <hip/hip_runtime.h>
#include <stdint.h>

// ---------------------------------------------------------------------------
// R7: R2's proven shape (4096 blocks x 256 thr x 64-px chunk) minus its
// overheads. 5 dispatches:
//   prep: per-chunk/per-group input histograms + weight transposes.
//   midA: layer0 via LUT (carry from histograms) + dense1 MFMA -> Y1.
//   midB: dense2 -> Y (in-place).
//   midC: dense3 + final dense via zero-padded-Wf MFMA -> out (local part).
//   fixk: out += INVN * Wf.carry3.
// Cross-chunk carries: per-chunk A64 rows + per-group (64 chunks) totals via
// atomicAdd; next dispatch's block prologue computes its own prefix with
// <=15 group rows + <=63 in-group rows SPLIT ACROSS 4 WAVES (parallel,
// coalesced) — no scanA dispatches, no per-wave serial 126-load loops (R6's
// killer), no lookback chains (R3's killer).
// ---------------------------------------------------------------------------

#define BB 4
#define SP 65536
#define SS 196608
#define CI 1024                 // 64-px chunks per batch
#define NG 16                   // groups per batch (64 chunks each)
#define INVN (1.0f / 196608.0f)

typedef __attribute__((ext_vector_type(8))) _Float16 half8;
typedef __attribute__((ext_vector_type(4))) float    f32x4;

// ---------------- prep: histograms + weight prep ----------------------------
__global__ __launch_bounds__(256)
void prep(const int* __restrict__ ex, const float* __restrict__ W0,
          const float* __restrict__ b0, const float* __restrict__ Wr,
          const float* __restrict__ Wfin,
          _Float16* __restrict__ Wt16, _Float16* __restrict__ Wf16p,
          float* __restrict__ Wf32, float* __restrict__ tab32,
          int* __restrict__ Hsub, int* __restrict__ Hgrp)
{
    __shared__ int hist[64][24];
    int tid = threadIdx.x, bi = blockIdx.x;
    int b = bi >> 4, g = bi & 15;              // group = 4096 px = 64 chunks
    for (int i = tid; i < 1536; i += 256) hist[i / 24][i % 24] = 0;
    __syncthreads();
    for (int q = 0; q < 16; ++q) {
        int pl = q * 256 + tid;                // 0..4095 within group
        const int* ep = ex + ((size_t)b * SP + g * 4096 + pl) * 3;
        int j = pl >> 6;                       // chunk within group
        atomicAdd(&hist[j][ep[0]], 1);
        atomicAdd(&hist[j][8 + ep[1]], 1);
        atomicAdd(&hist[j][16 + ep[2]], 1);
    }
    __syncthreads();
    for (int i = tid; i < 1536; i += 256) {
        int j = i / 24, cv = i % 24;
        Hsub[(size_t)(b * CI + g * 64 + j) * 24 + cv] = hist[j][cv];
    }
    if (tid < 24) {
        int s = 0;
        for (int j = 0; j < 64; ++j) s += hist[j][tid];
        Hgrp[(size_t)(b * NG + g) * 24 + tid] = s;
    }
    {   // weight prep (all 64 blocks share)
        int i0 = bi * 256 + tid, nth = 64 * 256;
        for (int idx = i0; idx < 36864; idx += nth) {   // Wt16[l][c][f][d]
            int d = idx & 63, f = (idx >> 6) & 63, lc = idx >> 12;
            Wt16[idx] = (_Float16)Wr[(size_t)(lc * 64 + d) * 64 + f];
        }
        for (int idx = i0; idx < 3072; idx += nth) {    // Wf16p[c][n16][d]
            int d = idx & 63, n = (idx >> 6) & 15, c = idx >> 10;
            Wf16p[idx] = (n < 8) ? (_Float16)Wfin[(size_t)(c * 64 + d) * 8 + n]
                                 : (_Float16)0.f;
        }
        for (int idx = i0; idx < 1536; idx += nth) {    // Wf32[ck][d]
            int d = idx & 63, ck = idx >> 6;
            Wf32[idx] = Wfin[(size_t)((ck >> 3) * 64 + d) * 8 + (ck & 7)];
        }
        for (int idx = i0; idx < 1536; idx += nth) {    // tab32[cv][f]
            int f = idx & 63, v = (idx >> 6) & 7, c = idx >> 9;
            float xv = v * 0.25f - 1.0f;
            tab32[idx] = fmaxf(W0[c * 64 + f] * xv + b0[c * 64 + f], 0.f);
        }
    }
}

// ---------------- midA: layer0 (LUT, hist carry) + dense1 -> Y --------------
__global__ __launch_bounds__(256, 4)
void midA(const int* __restrict__ ex,
          const int* __restrict__ Hsub, const int* __restrict__ Hgrp,
          const float* __restrict__ tab32,
          const _Float16* __restrict__ W16, const float* __restrict__ Wd32,
          const float* __restrict__ bias, _Float16* __restrict__ Y,
          float* __restrict__ A64, float* __restrict__ Ggrp)
{
    __shared__ float stab[1536];
    __shared__ __align__(16) _Float16 bounce3[3][64 * 72];
    __shared__ float segwt[3][4][64];
    __shared__ float basearr[192];
    __shared__ float hpart[4][24];
    __shared__ float carry[64];

    int tid = threadIdx.x, bi = blockIdx.x;
    int b = bi >> 10, ci = bi & 1023, g = ci >> 6, cr = ci & 63;
    int w = tid >> 6, ln = tid & 63, lm = ln & 15, lq = ln >> 4;
    int P0 = ci * 64;

    for (int i = tid; i < 1536; i += 256) stab[i] = tab32[i];
    if (ln < 24) {                             // distributed hist prefix
        float s = 0.f;
        for (int j = w; j < g; j += 4)
            s += (float)Hgrp[(size_t)(b * NG + j) * 24 + ln];
        const int* hp = Hsub + (size_t)(b * CI + g * 64) * 24 + ln;
        for (int j = w; j < cr; j += 4) s += (float)hp[j * 24];
        hpart[w][ln] = s;
    }
    __syncthreads();                           // B1: stab + hpart

    // layer-0 local values: thread (f=ln, seg=w) scans 16 px
    float y0[3][16];
    {
#pragma unroll
        for (int p = 0; p < 16; ++p) {
            const int* ep = ex + ((size_t)b * SP + P0 + w * 16 + p) * 3;
            y0[0][p] = stab[ep[0] * 64 + ln];
            y0[1][p] = stab[(8 + ep[1]) * 64 + ln];
            y0[2][p] = stab[(16 + ep[2]) * 64 + ln];
        }
#pragma unroll
        for (int c = 0; c < 3; ++c)
#pragma unroll
            for (int p = 1; p < 16; ++p) y0[c][p] += y0[c][p - 1];
#pragma unroll
        for (int c = 0; c < 3; ++c) segwt[c][w][ln] = y0[c][15];
    }
    if (tid < 64) {                            // layer-0 carry from hist
        float c0 = 0.f;
#pragma unroll
        for (int cv = 0; cv < 24; ++cv) {
            float cnt = hpart[0][cv] + hpart[1][cv] + hpart[2][cv] + hpart[3][cv];
            c0 += cnt * stab[cv * 64 + tid];
        }
        carry[tid] = c0;
    }
    __syncthreads();                           // B2: segwt + carry

    {   // combine channels -> bounce (layer-0 chunk-local flattened cumsum)
        float off0[3];
#pragma unroll
        for (int c = 0; c < 3; ++c) {
            float o = 0.f;
            for (int w2 = 0; w2 < w; ++w2) o += segwt[c][w2][ln];
            off0[c] = o;
        }
#pragma unroll
        for (int p = 0; p < 16; ++p) {
            float S0 = y0[0][p] + off0[0], S1 = y0[1][p] + off0[1], S2 = y0[2][p] + off0[2];
            float P1 = p ? y0[1][p - 1] + off0[1] : off0[1];
            float P2 = p ? y0[2][p - 1] + off0[2] : off0[2];
            int row = w * 16 + p;
            bounce3[0][row * 72 + ln] = (_Float16)(S0 + P1 + P2);
            bounce3[1][row * 72 + ln] = (_Float16)(S0 + S1 + P2);
            bounce3[2][row * 72 + ln] = (_Float16)(S0 + S1 + S2);
        }
    }
    if (tid < 192) {                           // basefold for dense1
        int c = tid >> 6, f = tid & 63;
        const float* wp = Wd32 + (size_t)(c * 64) * 64 + f;
        float a = 0.f;
        for (int d = 0; d < 64; ++d) a += carry[d] * wp[d * 64];
        basearr[tid] = bias[tid] + INVN * a;
    }
    __syncthreads();                           // B3: bounce + basearr

    // dense1 MFMA
    f32x4 acc[3][4];
#pragma unroll
    for (int c = 0; c < 3; ++c) {
        const half8* bb = (const half8*)&bounce3[c][0];
        half8 a0 = bb[(w * 16 + lm) * 9 + lq];
        half8 a1 = bb[(w * 16 + lm) * 9 + 4 + lq];
#pragma unroll
        for (int nt = 0; nt < 4; ++nt) {
            const half8* bp = (const half8*)(W16 + (size_t)(c * 64 + nt * 16 + lm) * 64);
            f32x4 t = {0.f, 0.f, 0.f, 0.f};
            t = __builtin_amdgcn_mfma_f32_16x16x32_f16(a0, bp[lq],     t, 0, 0, 0);
            t = __builtin_amdgcn_mfma_f32_16x16x32_f16(a1, bp[4 + lq], t, 0, 0, 0);
            acc[c][nt] = t;
        }
    }

    // relu + scan + shuffle
    float s[3][4][4], wexcl[3][4];
#pragma unroll
    for (int c = 0; c < 3; ++c)
#pragma unroll
        for (int nt = 0; nt < 4; ++nt) {
            float base = basearr[c * 64 + nt * 16 + lm];
            float run = 0.f;
#pragma unroll
            for (int r = 0; r < 4; ++r) {
                float yv = fmaxf(base + INVN * acc[c][nt][r], 0.f);
                run += yv; s[c][nt][r] = run;
            }
            float v = run;
            float t1 = __shfl_up(v, 16); if (lq >= 1) v += t1;
            float t2 = __shfl_up(v, 32); if (lq >= 2) v += t2;
            wexcl[c][nt] = v - run;
            if (lq == 3) segwt[c][w][nt * 16 + lm] = v;   // wave totals
        }
    __syncthreads();                           // B4: wave tops

    {
        float off[3][4], tot[3][4];
#pragma unroll
        for (int c = 0; c < 3; ++c)
#pragma unroll
            for (int nt = 0; nt < 4; ++nt) {
                float o = wexcl[c][nt], ts = 0.f;
#pragma unroll
                for (int w2 = 0; w2 < 4; ++w2) {
                    float wv = segwt[c][w2][nt * 16 + lm];
                    ts += wv;
                    if (w2 < w) o += wv;
                }
                off[c][nt] = o; tot[c][nt] = ts;
            }
        if (w == 0 && lq == 0)
#pragma unroll
            for (int nt = 0; nt < 4; ++nt) {
                float t3 = tot[0][nt] + tot[1][nt] + tot[2][nt];
                A64[(size_t)(b * CI + ci) * 64 + nt * 16 + lm] = t3;
                atomicAdd(&Ggrp[(size_t)(b * NG + g) * 64 + nt * 16 + lm], t3);
            }
#pragma unroll
        for (int nt = 0; nt < 4; ++nt)
#pragma unroll
            for (int r = 0; r < 4; ++r) {
                float S0 = off[0][nt] + s[0][nt][r];
                float S1 = off[1][nt] + s[1][nt][r];
                float S2 = off[2][nt] + s[2][nt][r];
                float P1 = off[1][nt] + (r ? s[1][nt][r - 1] : 0.f);
                float P2 = off[2][nt] + (r ? s[2][nt][r - 1] : 0.f);
                int row = w * 16 + lq * 4 + r;
                bounce3[0][row * 72 + nt * 16 + lm] = (_Float16)(S0 + P1 + P2);
                bounce3[1][row * 72 + nt * 16 + lm] = (_Float16)(S0 + S1 + P2);
                bounce3[2][row * 72 + nt * 16 + lm] = (_Float16)(S0 + S1 + S2);
            }
    }
    __syncthreads();                           // B5: store staging
#pragma unroll
    for (int q = 0; q < 6; ++q) {
        int idx = q * 256 + tid;
        int c = idx >> 9, rem = idx & 511;
        int pix = rem >> 3, f8 = rem & 7;
        half8 v = *(const half8*)&bounce3[c][pix * 72 + f8 * 8];
        ((half8*)(Y + ((size_t)(b * 3 + c) * SP + P0 + pix) * 64))[f8] = v;
    }
}

// ---------------- midB: dense2, Y in-place ----------------------------------
__global__ __launch_bounds__(256, 4)
void midB(const _Float16* Yin, _Float16* Yout,
          const float* __restrict__ A64p, const float* __restrict__ Ggrp_p,
          const _Float16* __restrict__ W16, const float* __restrict__ Wd32,
          const float* __restrict__ bias,
          float* __restrict__ A64, float* __restrict__ Ggrp)
{
    __shared__ __align__(16) _Float16 bounce3[3][64 * 72];
    __shared__ float wtop[3][4][64];
    __shared__ float basearr[192];
    __shared__ float cpart[4][64];
    __shared__ float carry[64];

    int tid = threadIdx.x, bi = blockIdx.x;
    int b = bi >> 10, ci = bi & 1023, g = ci >> 6, cr = ci & 63;
    int w = tid >> 6, ln = tid & 63, lm = ln & 15, lq = ln >> 4;
    int P0 = ci * 64;

    // A-frags first (latency hidden behind prologue)
    half8 af0[3], af1[3];
#pragma unroll
    for (int c = 0; c < 3; ++c) {
        const half8* ap = (const half8*)(Yin + ((size_t)(b * 3 + c) * SP + P0 + w * 16 + lm) * 64);
        af0[c] = ap[lq]; af1[c] = ap[4 + lq];
    }
    {   // distributed carry prefix
        float s = 0.f;
        for (int j = w; j < g; j += 4)
            s += Ggrp_p[(size_t)(b * NG + j) * 64 + ln];
        const float* ap = A64p + (size_t)(b * CI + g * 64) * 64 + ln;
        for (int j = w; j < cr; j += 4) s += ap[j * 64];
        cpart[w][ln] = s;
    }
    __syncthreads();                           // B1
    if (tid < 64)
        carry[tid] = cpart[0][tid] + cpart[1][tid] + cpart[2][tid] + cpart[3][tid];
    __syncthreads();                           // B2
    if (tid < 192) {
        int c = tid >> 6, f = tid & 63;
        const float* wp = Wd32 + (size_t)(c * 64) * 64 + f;
        float a = 0.f;
        for (int d = 0; d < 64; ++d) a += carry[d] * wp[d * 64];
        basearr[tid] = bias[tid] + INVN * a;
    }
    __syncthreads();                           // B3

    f32x4 acc[3][4];
#pragma unroll
    for (int c = 0; c < 3; ++c)
#pragma unroll
        for (int nt = 0; nt < 4; ++nt) {
            const half8* bp = (const half8*)(W16 + (size_t)(c * 64 + nt * 16 + lm) * 64);
            f32x4 t = {0.f, 0.f, 0.f, 0.f};
            t = __builtin_amdgcn_mfma_f32_16x16x32_f16(af0[c], bp[lq],     t, 0, 0, 0);
            t = __builtin_amdgcn_mfma_f32_16x16x32_f16(af1[c], bp[4 + lq], t, 0, 0, 0);
            acc[c][nt] = t;
        }

    float s[3][4][4], wexcl[3][4];
#pragma unroll
    for (int c = 0; c < 3; ++c)
#pragma unroll
        for (int nt = 0; nt < 4; ++nt) {
            float base = basearr[c * 64 + nt * 16 + lm];
            float run = 0.f;
#pragma unroll
            for (int r = 0; r < 4; ++r) {
                float yv = fmaxf(base + INVN * acc[c][nt][r], 0.f);
                run += yv; s[c][nt][r] = run;
            }
            float v = run;
            float t1 = __shfl_up(v, 16); if (lq >= 1) v += t1;
            float t2 = __shfl_up(v, 32); if (lq >= 2) v += t2;
            wexcl[c][nt] = v - run;
            if (lq == 3) wtop[c][w][nt * 16 + lm] = v;
        }
    __syncthreads();                           // B4

    {
        float off[3][4], tot[3][4];
#pragma unroll
        for (int c = 0; c < 3; ++c)
#pragma unroll
            for (int nt = 0; nt < 4; ++nt) {
                float o = wexcl[c][nt], ts = 0.f;
#pragma unroll
                for (int w2 = 0; w2 < 4; ++w2) {
                    float wv = wtop[c][w2][nt * 16 + lm];
                    ts += wv;
                    if (w2 < w) o += wv;
                }
                off[c][nt] = o; tot[c][nt] = ts;
            }
        if (w == 0 && lq == 0)
#pragma unroll
            for (int nt = 0; nt < 4; ++nt) {
                float t3 = tot[0][nt] + tot[1][nt] + tot[2][nt];
                A64[(size_t)(b * CI + ci) * 64 + nt * 16 + lm] = t3;
                atomicAdd(&Ggrp[(size_t)(b * NG + g) * 64 + nt * 16 + lm], t3);
            }
#pragma unroll
        for (int nt = 0; nt < 4; ++nt)
#pragma unroll
            for (int r = 0; r < 4; ++r) {
                float S0 = off[0][nt] + s[0][nt][r];
                float S1 = off[1][nt] + s[1][nt][r];
                float S2 = off[2][nt] + s[2][nt][r];
                float P1 = off[1][nt] + (r ? s[1][nt][r - 1] : 0.f);
                float P2 = off[2][nt] + (r ? s[2][nt][r - 1] : 0.f);
                int row = w * 16 + lq * 4 + r;
                bounce3[0][row * 72 + nt * 16 + lm] = (_Float16)(S0 + P1 + P2);
                bounce3[1][row * 72 + nt * 16 + lm] = (_Float16)(S0 + S1 + P2);
                bounce3[2][row * 72 + nt * 16 + lm] = (_Float16)(S0 + S1 + S2);
            }
    }
    __syncthreads();                           // B5
#pragma unroll
    for (int q = 0; q < 6; ++q) {
        int idx = q * 256 + tid;
        int c = idx >> 9, rem = idx & 511;
        int pix = rem >> 3, f8 = rem & 7;
        half8 v = *(const half8*)&bounce3[c][pix * 72 + f8 * 8];
        ((half8*)(Yout + ((size_t)(b * 3 + c) * SP + P0 + pix) * 64))[f8] = v;
    }
}

// ---------------- midC: dense3 + final MFMA -> out (local part) -------------
__global__ __launch_bounds__(256, 4)
void midC(const _Float16* __restrict__ Yin,
          const float* __restrict__ A64p, const float* __restrict__ Ggrp_p,
          const _Float16* __restrict__ W16, const float* __restrict__ Wd32,
          const float* __restrict__ bias,
          const _Float16* __restrict__ Wf16p, const float* __restrict__ bfin,
          float* __restrict__ out, float* __restrict__ A64, float* __restrict__ Ggrp)
{
    __shared__ __align__(16) _Float16 bounce3[3][64 * 72];
    __shared__ float wtop[3][4][64];
    __shared__ float basearr[192];
    __shared__ float cpart[4][64];
    __shared__ float carry[64];
    __shared__ __align__(16) float outst[64 * 28];

    int tid = threadIdx.x, bi = blockIdx.x;
    int b = bi >> 10, ci = bi & 1023, g = ci >> 6, cr = ci & 63;
    int w = tid >> 6, ln = tid & 63, lm = ln & 15, lq = ln >> 4;
    int P0 = ci * 64;

    half8 af0[3], af1[3];
#pragma unroll
    for (int c = 0; c < 3; ++c) {
        const half8* ap = (const half8*)(Yin + ((size_t)(b * 3 + c) * SP + P0 + w * 16 + lm) * 64);
        af0[c] = ap[lq]; af1[c] = ap[4 + lq];
    }
    {
        float s = 0.f;
        for (int j = w; j < g; j += 4)
            s += Ggrp_p[(size_t)(b * NG + j) * 64 + ln];
        const float* ap = A64p + (size_t)(b * CI + g * 64) * 64 + ln;
        for (int j = w; j < cr; j += 4) s += ap[j * 64];
        cpart[w][ln] = s;
    }
    __syncthreads();                           // B1
    if (tid < 64)
        carry[tid] = cpart[0][tid] + cpart[1][tid] + cpart[2][tid] + cpart[3][tid];
    __syncthreads();                           // B2
    if (tid < 192) {
        int c = tid >> 6, f = tid & 63;
        const float* wp = Wd32 + (size_t)(c * 64) * 64 + f;
        float a = 0.f;
        for (int d = 0; d < 64; ++d) a += carry[d] * wp[d * 64];
        basearr[tid] = bias[tid] + INVN * a;
    }
    __syncthreads();                           // B3

    f32x4 acc[3][4];
#pragma unroll
    for (int c = 0; c < 3; ++c)
#pragma unroll
        for (int nt = 0; nt < 4; ++nt) {
            const half8* bp = (const half8*)(W16 + (size_t)(c * 64 + nt * 16 + lm) * 64);
            f32x4 t = {0.f, 0.f, 0.f, 0.f};
            t = __builtin_amdgcn_mfma_f32_16x16x32_f16(af0[c], bp[lq],     t, 0, 0, 0);
            t = __builtin_amdgcn_mfma_f32_16x16x32_f16(af1[c], bp[4 + lq], t, 0, 0, 0);
            acc[c][nt] = t;
        }

    float s[3][4][4], wexcl[3][4];
#pragma unroll
    for (int c = 0; c < 3; ++c)
#pragma unroll
        for (int nt = 0; nt < 4; ++nt) {
            float base = basearr[c * 64 + nt * 16 + lm];
            float run = 0.f;
#pragma unroll
            for (int r = 0; r < 4; ++r) {
                float yv = fmaxf(base + INVN * acc[c][nt][r], 0.f);
                run += yv; s[c][nt][r] = run;
            }
            float v = run;
            float t1 = __shfl_up(v, 16); if (lq >= 1) v += t1;
            float t2 = __shfl_up(v, 32); if (lq >= 2) v += t2;
            wexcl[c][nt] = v - run;
            if (lq == 3) wtop[c][w][nt * 16 + lm] = v;
        }
    __syncthreads();                           // B4

    {
        float off[3][4], tot[3][4];
#pragma unroll
        for (int c = 0; c < 3; ++c)
#pragma unroll
            for (int nt = 0; nt < 4; ++nt) {
                float o = wexcl[c][nt], ts = 0.f;
#pragma unroll
                for (int w2 = 0; w2 < 4; ++w2) {
                    float wv = wtop[c][w2][nt * 16 + lm];
                    ts += wv;
                    if (w2 < w) o += wv;
                }
                off[c][nt] = o; tot[c][nt] = ts;
            }
        if (w == 0 && lq == 0)
#pragma unroll
            for (int nt = 0; nt < 4; ++nt) {
                float t3 = tot[0][nt] + tot[1][nt] + tot[2][nt];
                A64[(size_t)(b * CI + ci) * 64 + nt * 16 + lm] = t3;
                atomicAdd(&Ggrp[(size_t)(b * NG + g) * 64 + nt * 16 + lm], t3);
            }
#pragma unroll
        for (int nt = 0; nt < 4; ++nt)
#pragma unroll
            for (int r = 0; r < 4; ++r) {
                float S0 = off[0][nt] + s[0][nt][r];
                float S1 = off[1][nt] + s[1][nt][r];
                float S2 = off[2][nt] + s[2][nt][r];
                float P1 = off[1][nt] + (r ? s[1][nt][r - 1] : 0.f);
                float P2 = off[2][nt] + (r ? s[2][nt][r - 1] : 0.f);
                int row = w * 16 + lq * 4 + r;
                bounce3[0][row * 72 + nt * 16 + lm] = (_Float16)(S0 + P1 + P2);
                bounce3[1][row * 72 + nt * 16 + lm] = (_Float16)(S0 + S1 + P2);
                bounce3[2][row * 72 + nt * 16 + lm] = (_Float16)(S0 + S1 + S2);
            }
    }
    __syncthreads();                           // B5: layer-3 local staged

    // final dense via padded-Wf MFMA (n=16: 8 logits + 8 zero)
#pragma unroll
    for (int c = 0; c < 3; ++c) {
        const half8* bb = (const half8*)&bounce3[c][0];
        half8 fa0 = bb[(w * 16 + lm) * 9 + lq];
        half8 fa1 = bb[(w * 16 + lm) * 9 + 4 + lq];
        const half8* fb = (const half8*)(Wf16p + (size_t)(c * 16 + lm) * 64);
        f32x4 t = {0.f, 0.f, 0.f, 0.f};
        t = __builtin_amdgcn_mfma_f32_16x16x32_f16(fa0, fb[lq],     t, 0, 0, 0);
        t = __builtin_amdgcn_mfma_f32_16x16x32_f16(fa1, fb[4 + lq], t, 0, 0, 0);
        if (lm < 8) {
            float bz = bfin[c * 8 + lm];
#pragma unroll
            for (int r = 0; r < 4; ++r)
                outst[(w * 16 + lq * 4 + r) * 28 + c * 8 + lm] = bz + INVN * t[r];
        }
    }
    __syncthreads();                           // B6
    {   // 64 px x 24 floats = 384 float4
        float4* obase = (float4*)(out + ((size_t)b * SS + (size_t)P0 * 3) * 8);
#pragma unroll
        for (int k = 0; k < 2; ++k) {
            int idx = k * 256 + tid;
            if (idx < 384) {
                int pix = idx / 6, sub = (idx % 6) * 4;
                obase[idx] = *(const float4*)&outst[pix * 28 + sub];
            }
        }
    }
}

// ---------------- fixk: out += INVN * Wf . carry3 ---------------------------
__global__ __launch_bounds__(256, 4)
void fixk(const float* __restrict__ A64p, const float* __restrict__ Ggrp_p,
          const float* __restrict__ Wf32, float* __restrict__ out)
{
    __shared__ float cpart[4][64];
    __shared__ float carry[64];
    __shared__ float vfix[24];
    int tid = threadIdx.x, bi = blockIdx.x;
    int b = bi >> 10, ci = bi & 1023, g = ci >> 6, cr = ci & 63;
    int w = tid >> 6, ln = tid & 63;
    int P0 = ci * 64;

    {
        float s = 0.f;
        for (int j = w; j < g; j += 4)
            s += Ggrp_p[(size_t)(b * NG + j) * 64 + ln];
        const float* ap = A64p + (size_t)(b * CI + g * 64) * 64 + ln;
        for (int j = w; j < cr; j += 4) s += ap[j * 64];
        cpart[w][ln] = s;
    }
    __syncthreads();
    if (tid < 64)
        carry[tid] = cpart[0][tid] + cpart[1][tid] + cpart[2][tid] + cpart[3][tid];
    __syncthreads();
    if (tid < 24) {
        float vf = 0.f;
        for (int d = 0; d < 64; ++d) vf += carry[d] * Wf32[tid * 64 + d];
        vfix[tid] = INVN * vf;
    }
    __syncthreads();
    float4* obase = (float4*)(out + ((size_t)b * SS + (size_t)P0 * 3) * 8);
#pragma unroll
    for (int k = 0; k < 2; ++k) {
        int idx = k * 256 + tid;
        if (idx < 384) {
            int sub = (idx % 6) * 4;
            float4 v = obase[idx];
            v.x += vfix[sub];
            v.y += vfix[sub + 1];
            v.z += vfix[sub + 2];
            v.w += vfix[sub + 3];
            obase[idx] = v;
        }
    }
}

// ---------------- host -------------------------------------------------------
extern "C" void kernel_launch(void* const* d_in, const int* in_sizes, int n_in,
                              void* d_out, int out_size, void* d_ws, size_t ws_size,
                              hipStream_t stream)
{
    const int*   ex   = (const int*)d_in[0];
    const float* W0   = (const float*)d_in[1];
    const float* b0   = (const float*)d_in[2];
    const float* Wr   = (const float*)d_in[3];
    const float* br   = (const float*)d_in[4];
    const float* Wfin = (const float*)d_in[5];
    const float* bfin = (const float*)d_in[6];
    float* out = (float*)d_out;

    char* ws = (char*)d_ws;
    size_t off = 0;
    _Float16* Y = (_Float16*)(ws + off); off += (size_t)BB * 3 * SP * 64 * 2;  // 100.7 MB
    float* Ggrp1 = (float*)(ws + off); off += (size_t)BB * NG * 64 * 4;        // contiguous
    float* Ggrp2 = (float*)(ws + off); off += (size_t)BB * NG * 64 * 4;
    float* Ggrp3 = (float*)(ws + off); off += (size_t)BB * NG * 64 * 4;
    float* A64_1 = (float*)(ws + off); off += (size_t)BB * CI * 64 * 4;
    float* A64_2 = (float*)(ws + off); off += (size_t)BB * CI * 64 * 4;
    float* A64_3 = (float*)(ws + off); off += (size_t)BB * CI * 64 * 4;
    int* Hsub = (int*)(ws + off); off += (size_t)BB * CI * 24 * 4;
    int* Hgrp = (int*)(ws + off); off += (size_t)BB * NG * 24 * 4;
    _Float16* Wt16  = (_Float16*)(ws + off); off += 36864 * 2;
    _Float16* Wf16p = (_Float16*)(ws + off); off += 3072 * 2;
    float* Wf32  = (float*)(ws + off); off += 1536 * 4;
    float* tab32 = (float*)(ws + off); off += 1536 * 4;

    hipMemsetAsync(Ggrp1, 0, 3 * (size_t)BB * NG * 64 * 4, stream);
    prep<<<64, 256, 0, stream>>>(ex, W0, b0, Wr, Wfin,
                                 Wt16, Wf16p, Wf32, tab32, Hsub, Hgrp);
    midA<<<4096, 256, 0, stream>>>(ex, Hsub, Hgrp, tab32,
                                   Wt16, Wr, br, Y, A64_1, Ggrp1);
    midB<<<4096, 256, 0, stream>>>(Y, Y, A64_1, Ggrp1,
                                   Wt16 + 12288, Wr + 12288, br + 192,
                                   A64_2, Ggrp2);
    midC<<<4096, 256, 0, stream>>>(Y, A64_2, Ggrp2,
                                   Wt16 + 24576, Wr + 24576, br + 384,
                                   Wf16p, bfin, out, A64_3, Ggrp3);
    fixk<<<4096, 256, 0, stream>>>(A64_3, Ggrp3, Wf32, out);
}